// Round 6
// baseline (220.956 us; speedup 1.0000x reference)
//
#include <hip/hip_runtime.h>
#include <hip/hip_bf16.h>
#include <math.h>

#define NNODES 50000
#define NEDGES 800000
#define IN1 512
#define IN2 256
#define NOUT 128
#define FTOT 256   // combined feature width (two GCN branches)

typedef __attribute__((ext_vector_type(4))) short short4v;
typedef __attribute__((ext_vector_type(8))) short frag_ab;
typedef __attribute__((ext_vector_type(4))) float frag_cd;

// ---------------- workspace layout (bytes) ----------------
#define OFF_XW      ((size_t)0)           // N*256 bf16 = 25,600,000 (pre-scaled by dinv[row])
#define OFF_W1T     ((size_t)25600000)    // 128x512 bf16 [col][k]
#define OFF_W2T     ((size_t)25731072)    // 128x256 bf16 [col][k]
#define OFF_DEG     ((size_t)25796608)    // N int
#define OFF_DINV    ((size_t)25996672)    // N f32
#define OFF_ROWPTR  ((size_t)26196736)    // (N+1) int
#define OFF_CURSOR  ((size_t)26396800)    // N int
#define OFF_BSUM    ((size_t)26596864)    // 256 int
#define OFF_ADJ     ((size_t)26600960)    // E int

__device__ __forceinline__ short f2bf(float f) {
    union { float f; unsigned u; } x; x.f = f;
    unsigned r = x.u + 0x7fffu + ((x.u >> 16) & 1u);   // RNE
    return (short)(r >> 16);
}
__device__ __forceinline__ float bf2f(unsigned short u) {
    union { unsigned u; float f; } x; x.u = ((unsigned)u) << 16;
    return x.f;
}

// ---------------- small kernels ----------------

// W transpose/convert + deg zeroing (folds the old memset dispatch)
__global__ __launch_bounds__(256) void wcvt_kernel(const float* __restrict__ W1, const float* __restrict__ W2,
                                                   short* __restrict__ w1t, short* __restrict__ w2t,
                                                   int* __restrict__ deg, int n) {
    int t = blockIdx.x * 256 + threadIdx.x;
    if (t < n) deg[t] = 0;
    if (t < IN1 * NOUT) {
        int c = t & 127, k = t >> 7;
        w1t[c * IN1 + k] = f2bf(W1[t]);
    } else if (t < (IN1 + IN2) * NOUT) {
        int u = t - IN1 * NOUT;
        int c = u & 127, k = u >> 7;
        w2t[c * IN2 + k] = f2bf(W2[u]);
    }
}

__global__ __launch_bounds__(256) void hist_kernel(const int* __restrict__ ei, int* __restrict__ deg, int e) {
    int i = blockIdx.x * blockDim.x + threadIdx.x;
    if (i < e) atomicAdd(&deg[ei[e + i]], 1);
}

__global__ __launch_bounds__(256) void scan_part_kernel(const int* __restrict__ deg, float* __restrict__ dinv,
                                                        int* __restrict__ bsum, int n) {
    __shared__ int s[256];
    int t = threadIdx.x;
    int i = blockIdx.x * 256 + t;
    int v = (i < n) ? deg[i] : 0;
    if (i < n) dinv[i] = rsqrtf((float)(v + 1));
    s[t] = v; __syncthreads();
    #pragma unroll
    for (int off = 128; off > 0; off >>= 1) {
        if (t < off) s[t] += s[t + off];
        __syncthreads();
    }
    if (t == 0) bsum[blockIdx.x] = s[0];
}

__global__ __launch_bounds__(256) void scan_top_kernel(int* __restrict__ bsum, int nb) {
    __shared__ int s[256];
    int t = threadIdx.x;
    int v = (t < nb) ? bsum[t] : 0;
    s[t] = v; __syncthreads();
    for (int off = 1; off < 256; off <<= 1) {
        int u = (t >= off) ? s[t - off] : 0;
        __syncthreads();
        s[t] += u;
        __syncthreads();
    }
    if (t < nb) bsum[t] = s[t] - v;
}

__global__ __launch_bounds__(256) void scan_write_kernel(const int* __restrict__ deg, const int* __restrict__ bsum,
                                                         int* __restrict__ rowptr, int* __restrict__ cursor, int n) {
    __shared__ int s[256];
    int t = threadIdx.x;
    int i = blockIdx.x * 256 + t;
    int v = (i < n) ? deg[i] : 0;
    s[t] = v; __syncthreads();
    for (int off = 1; off < 256; off <<= 1) {
        int u = (t >= off) ? s[t - off] : 0;
        __syncthreads();
        s[t] += u;
        __syncthreads();
    }
    int base = bsum[blockIdx.x];
    if (i < n) { int rp = base + s[t] - v; rowptr[i] = rp; cursor[i] = rp; }
    if (i == n - 1) rowptr[n] = base + s[t];
}

__global__ __launch_bounds__(256) void fill_kernel(const int* __restrict__ ei,
                                                   int* __restrict__ cursor, int* __restrict__ adj, int e) {
    int i = blockIdx.x * blockDim.x + threadIdx.x;
    if (i < e) {
        int src = ei[i];
        int dst = ei[e + i];
        int pos = atomicAdd(&cursor[dst], 1);
        adj[pos] = src;
    }
}

// ---------------- MFMA GEMM v3: BK=128 for DRAM-friendly A reads ----------------
// BM=128, BN=128, BK=128, single-buffered LDS (64 KiB -> 2 blocks/CU), 4 waves
// (2x2, 64x64 each), 2 barriers/K-step, NT = K/128 steps (4 for mod1, 2 mod2).
// Per stage, a wave's A-load instruction covers TWO COMPLETE 512B row-slices
// (contiguous) -- the diagnosis from R2-R5 is that 256B-at-2KB-stride K-slices
// throttled the HBM-sourced portion to ~1 TB/s.
#define GBM 128
#define GBK 128

template<int K, int COLOFF>
__device__ __forceinline__ void gemm_tile(const float* __restrict__ X, const short* __restrict__ Wt,
                                          const float* __restrict__ dinv, short* __restrict__ xw,
                                          short (*As)[128][8], short (*Bs)[128][8],
                                          int tileIdx, int n) {
    constexpr int NT = K / GBK;
    const int t    = threadIdx.x;
    const int lane = t & 63;
    const int wave = t >> 6;
    const int wr   = wave >> 1, wc = wave & 1;
    const int l15  = lane & 15, kof = lane >> 4;
    const int rowBase = tileIdx * GBM;

    // A staging: instr j covers rows {w*32+2j, w*32+2j+1}; lane reads float4
    // a_f4 of its row's 512B k-slice -> fully sequential per row.
    const int a_w    = t >> 6;
    const int a_half = (t >> 5) & 1;
    const int a_f4   = t & 31;          // float4 index in k-slice (0..31)
    const int a_k8   = a_f4 >> 1;       // k8 chunk 0..15
    const int a_j4   = (a_f4 & 1) * 4;  // short offset 0 or 4
    // B staging (R5-style, proven 0-conflict): col b_c0+32i, k8 = b_k8l + 8*kh
    const int b_k8l = t & 7;
    const int b_c0  = t >> 3;           // 0..31

    frag_cd acc[4][4];
    #pragma unroll
    for (int i = 0; i < 4; ++i)
        #pragma unroll
        for (int j = 0; j < 4; ++j)
            acc[i][j] = (frag_cd){0.f, 0.f, 0.f, 0.f};

    auto stage = [&](int kt) {
        float4 av[16];
        #pragma unroll
        for (int j = 0; j < 16; ++j) {
            int g = rowBase + a_w * 32 + 2 * j + a_half;
            if (g >= n) g = n - 1;
            av[j] = *reinterpret_cast<const float4*>(X + (size_t)g * K + kt + a_f4 * 4);
        }
        frag_ab bv[8];
        #pragma unroll
        for (int i = 0; i < 4; ++i)
            #pragma unroll
            for (int kh = 0; kh < 2; ++kh)
                bv[i * 2 + kh] = *reinterpret_cast<const frag_ab*>(
                    Wt + (size_t)(b_c0 + i * 32) * K + kt + (b_k8l + kh * 8) * 8);
        #pragma unroll
        for (int j = 0; j < 16; ++j) {
            int r = a_w * 32 + 2 * j + a_half;
            short4v p;
            p[0] = f2bf(av[j].x); p[1] = f2bf(av[j].y);
            p[2] = f2bf(av[j].z); p[3] = f2bf(av[j].w);
            *reinterpret_cast<short4v*>(&As[a_k8][r ^ a_k8][a_j4]) = p;
        }
        #pragma unroll
        for (int i = 0; i < 4; ++i)
            #pragma unroll
            for (int kh = 0; kh < 2; ++kh) {
                int k8 = b_k8l + kh * 8;
                *reinterpret_cast<frag_ab*>(&Bs[k8][(b_c0 + i * 32) ^ k8][0]) = bv[i * 2 + kh];
            }
    };

    stage(0);
    for (int it = 0; it < NT; ++it) {
        __syncthreads();   // stage complete for all

        __builtin_amdgcn_s_setprio(1);
        #pragma unroll
        for (int ks = 0; ks < 4; ++ks) {
            const int k8a = ks * 4 + kof;
            frag_ab afr[4], bfr[4];
            #pragma unroll
            for (int mf = 0; mf < 4; ++mf)
                afr[mf] = *reinterpret_cast<const frag_ab*>(&As[k8a][(wr * 64 + mf * 16 + l15) ^ k8a][0]);
            #pragma unroll
            for (int nf = 0; nf < 4; ++nf)
                bfr[nf] = *reinterpret_cast<const frag_ab*>(&Bs[k8a][(wc * 64 + nf * 16 + l15) ^ k8a][0]);
            #pragma unroll
            for (int mf = 0; mf < 4; ++mf)
                #pragma unroll
                for (int nf = 0; nf < 4; ++nf)
                    acc[mf][nf] = __builtin_amdgcn_mfma_f32_16x16x32_bf16(bfr[nf], afr[mf], acc[mf][nf], 0, 0, 0);
        }
        __builtin_amdgcn_s_setprio(0);

        if (it + 1 < NT) {
            __syncthreads();          // all readers done -> safe to overwrite
            stage((it + 1) * GBK);
        }
    }

    // epilogue: lane holds out[row][cols kof*4..+3 of each frag]; pre-scale by dinv[row]
    #pragma unroll
    for (int mf = 0; mf < 4; ++mf) {
        int orow = rowBase + wr * 64 + mf * 16 + l15;
        if (orow < n) {
            float di = dinv[orow];
            short* dst = xw + (size_t)orow * FTOT + COLOFF + wc * 64 + kof * 4;
            #pragma unroll
            for (int nf = 0; nf < 4; ++nf) {
                short4v pk;
                pk[0] = f2bf(acc[mf][nf][0] * di); pk[1] = f2bf(acc[mf][nf][1] * di);
                pk[2] = f2bf(acc[mf][nf][2] * di); pk[3] = f2bf(acc[mf][nf][3] * di);
                *reinterpret_cast<short4v*>(dst + nf * 16) = pk;
            }
        }
    }
}

__global__ __launch_bounds__(256) void gemm_kernel(const float* __restrict__ x1, const float* __restrict__ x2,
                                                   const short* __restrict__ w1t, const short* __restrict__ w2t,
                                                   const float* __restrict__ dinv, short* __restrict__ xw,
                                                   int n, int t1b) {
    __shared__ short As[16][128][8];   // 32 KiB
    __shared__ short Bs[16][128][8];   // 32 KiB
    int b = blockIdx.x;
    if (b < t1b) gemm_tile<IN1, 0>(x1, w1t, dinv, xw, As, Bs, b, n);
    else         gemm_tile<IN2, 128>(x2, w2t, dinv, xw, As, Bs, b - t1b, n);
}

// ---------------- gather + epilogue ----------------
// one wave per node; xw rows are pre-scaled by dinv[src] -> plain sum.
__global__ __launch_bounds__(256) void gather_kernel(const unsigned short* __restrict__ xw,
                                                     const int* __restrict__ rowptr,
                                                     const int* __restrict__ adj,
                                                     const float* __restrict__ dinv,
                                                     const float* __restrict__ b1,
                                                     const float* __restrict__ b2,
                                                     float* __restrict__ out, int n) {
    int wid  = (int)((blockIdx.x * (size_t)blockDim.x + threadIdx.x) >> 6);
    int lane = threadIdx.x & 63;
    if (wid >= n) return;

    const ushort4* base = reinterpret_cast<const ushort4*>(xw);
    float ax = 0.f, ay = 0.f, az = 0.f, aw = 0.f;

    const int s = rowptr[wid], e = rowptr[wid + 1];
    int i = s;
    for (; i + 3 < e; i += 4) {                       // 4 independent row loads in flight
        int s0 = adj[i], s1 = adj[i + 1], s2 = adj[i + 2], s3 = adj[i + 3];
        ushort4 v0 = base[(size_t)s0 * 64 + lane];
        ushort4 v1 = base[(size_t)s1 * 64 + lane];
        ushort4 v2 = base[(size_t)s2 * 64 + lane];
        ushort4 v3 = base[(size_t)s3 * 64 + lane];
        ax += bf2f(v0.x) + bf2f(v1.x) + bf2f(v2.x) + bf2f(v3.x);
        ay += bf2f(v0.y) + bf2f(v1.y) + bf2f(v2.y) + bf2f(v3.y);
        az += bf2f(v0.z) + bf2f(v1.z) + bf2f(v2.z) + bf2f(v3.z);
        aw += bf2f(v0.w) + bf2f(v1.w) + bf2f(v2.w) + bf2f(v3.w);
    }
    for (; i < e; ++i) {
        int s0 = adj[i];
        ushort4 v0 = base[(size_t)s0 * 64 + lane];
        ax += bf2f(v0.x); ay += bf2f(v0.y); az += bf2f(v0.z); aw += bf2f(v0.w);
    }
    {   // self-loop (xw already has dinv[node] folded in)
        ushort4 v = base[(size_t)wid * 64 + lane];
        ax += bf2f(v.x); ay += bf2f(v.y); az += bf2f(v.z); aw += bf2f(v.w);
    }
    float di = dinv[wid];
    float4 bias = (lane < 32) ? reinterpret_cast<const float4*>(b1)[lane]
                              : reinterpret_cast<const float4*>(b2)[lane - 32];
    float4 v;
    v.x = fmaxf(fmaf(ax, di, bias.x), 0.f);
    v.y = fmaxf(fmaf(ay, di, bias.y), 0.f);
    v.z = fmaxf(fmaf(az, di, bias.z), 0.f);
    v.w = fmaxf(fmaf(aw, di, bias.w), 0.f);

    float4 h;
    h.x = v.x + __shfl_xor(v.x, 32);
    h.y = v.y + __shfl_xor(v.y, 32);
    h.z = v.z + __shfl_xor(v.z, 32);
    h.w = v.w + __shfl_xor(v.w, 32);

    float m = fmaxf(fmaxf(h.x, h.y), fmaxf(h.z, h.w));
    #pragma unroll
    for (int off = 1; off <= 16; off <<= 1) m = fmaxf(m, __shfl_xor(m, off));
    float ssum = __expf(h.x - m) + __expf(h.y - m) + __expf(h.z - m) + __expf(h.w - m);
    #pragma unroll
    for (int off = 1; off <= 16; off <<= 1) ssum += __shfl_xor(ssum, off);
    float lse = m + __logf(ssum);

    if (lane < 32) {
        float4 y;
        y.x = h.x - lse; y.y = h.y - lse; y.z = h.z - lse; y.w = h.w - lse;
        reinterpret_cast<float4*>(out)[(size_t)wid * 32 + lane] = y;
    }
}

// ---------------- launcher ----------------
extern "C" void kernel_launch(void* const* d_in, const int* in_sizes, int n_in,
                              void* d_out, int out_size, void* d_ws, size_t ws_size,
                              hipStream_t stream) {
    const float* x1 = (const float*)d_in[0];
    const float* x2 = (const float*)d_in[1];
    const int*   ei = (const int*)d_in[2];
    const float* W1 = (const float*)d_in[3];
    const float* b1 = (const float*)d_in[4];
    const float* W2 = (const float*)d_in[5];
    const float* b2 = (const float*)d_in[6];
    float* out = (float*)d_out;

    const int n = in_sizes[0] / IN1;       // 50000
    const int e = in_sizes[2] / 2;         // 800000

    char* ws = (char*)d_ws;
    short* xw     = (short*)(ws + OFF_XW);
    short* w1t    = (short*)(ws + OFF_W1T);
    short* w2t    = (short*)(ws + OFF_W2T);
    int*   deg    = (int*)  (ws + OFF_DEG);
    float* dinv   = (float*)(ws + OFF_DINV);
    int*   rowptr = (int*)  (ws + OFF_ROWPTR);
    int*   cursor = (int*)  (ws + OFF_CURSOR);
    int*   bsum   = (int*)  (ws + OFF_BSUM);
    int*   adj    = (int*)  (ws + OFF_ADJ);

    const int nb_n = (n + 255) / 256;      // 196
    const int nb_e = (e + 255) / 256;

    wcvt_kernel<<<((IN1 + IN2) * NOUT + 255) / 256, 256, 0, stream>>>(W1, W2, w1t, w2t, deg, n);
    hist_kernel<<<nb_e, 256, 0, stream>>>(ei, deg, e);
    scan_part_kernel<<<nb_n, 256, 0, stream>>>(deg, dinv, bsum, n);
    scan_top_kernel<<<1, 256, 0, stream>>>(bsum, nb_n);
    scan_write_kernel<<<nb_n, 256, 0, stream>>>(deg, bsum, rowptr, cursor, n);
    fill_kernel<<<nb_e, 256, 0, stream>>>(ei, cursor, adj, e);

    const int t1b = (n + GBM - 1) / GBM;   // 391 (mod1, K=512, launched first: LPT)
    const int t2b = (n + GBM - 1) / GBM;   // 391 (mod2, K=256)
    gemm_kernel<<<t1b + t2b, 256, 0, stream>>>(x1, x2, w1t, w2t, dinv, xw, n, t1b);

    const int waves_per_block = 4;
    int gb = (n + waves_per_block - 1) / waves_per_block;
    gather_kernel<<<gb, 256, 0, stream>>>((const unsigned short*)xw, rowptr, adj, dinv, b1, b2, out, n);
}

// Round 7
// 204.129 us; speedup vs baseline: 1.0824x; 1.0824x over previous
//
#include <hip/hip_runtime.h>
#include <hip/hip_bf16.h>
#include <math.h>

#define NNODES 50000
#define NEDGES 800000
#define IN1 512
#define IN2 256
#define NOUT 128
#define FTOT 256   // combined feature width (two GCN branches)

typedef __attribute__((ext_vector_type(4))) short short4v;
typedef __attribute__((ext_vector_type(8))) short frag_ab;
typedef __attribute__((ext_vector_type(4))) float frag_cd;

// ---------------- workspace layout (bytes) ----------------
#define OFF_XW      ((size_t)0)           // N*256 bf16 = 25,600,000
#define OFF_W1T     ((size_t)25600000)    // 128x512 bf16 [col][k]
#define OFF_W2T     ((size_t)25731072)    // 128x256 bf16 [col][k]
#define OFF_DEG     ((size_t)25796608)    // N int
#define OFF_DINV    ((size_t)25996672)    // N f32
#define OFF_ROWPTR  ((size_t)26196736)    // (N+1) int
#define OFF_CURSOR  ((size_t)26396800)    // N int
#define OFF_BSUM    ((size_t)26596864)    // 256 int
#define OFF_ADJ     ((size_t)26600960)    // E int

__device__ __forceinline__ short f2bf(float f) {
    union { float f; unsigned u; } x; x.f = f;
    unsigned r = x.u + 0x7fffu + ((x.u >> 16) & 1u);   // RNE
    return (short)(r >> 16);
}
__device__ __forceinline__ float bf2f(unsigned short u) {
    union { unsigned u; float f; } x; x.u = ((unsigned)u) << 16;
    return x.f;
}

// raw barrier that does NOT drain vmcnt: only LDS ops must complete.
// (rule #18: sched_barrier fences around the inline-asm wait)
__device__ __forceinline__ void sync_lds() {
    asm volatile("s_waitcnt lgkmcnt(0)" ::: "memory");
    __builtin_amdgcn_sched_barrier(0);
    __builtin_amdgcn_s_barrier();
    __builtin_amdgcn_sched_barrier(0);
}

// ---------------- small kernels ----------------

// W transpose/convert + deg zeroing
__global__ __launch_bounds__(256) void wcvt_kernel(const float* __restrict__ W1, const float* __restrict__ W2,
                                                   short* __restrict__ w1t, short* __restrict__ w2t,
                                                   int* __restrict__ deg, int n) {
    int t = blockIdx.x * 256 + threadIdx.x;
    if (t < n) deg[t] = 0;
    if (t < IN1 * NOUT) {
        int c = t & 127, k = t >> 7;
        w1t[c * IN1 + k] = f2bf(W1[t]);
    } else if (t < (IN1 + IN2) * NOUT) {
        int u = t - IN1 * NOUT;
        int c = u & 127, k = u >> 7;
        w2t[c * IN2 + k] = f2bf(W2[u]);
    }
}

__global__ __launch_bounds__(256) void scan_part_kernel(const int* __restrict__ deg, float* __restrict__ dinv,
                                                        int* __restrict__ bsum, int n) {
    __shared__ int s[256];
    int t = threadIdx.x;
    int i = blockIdx.x * 256 + t;
    int v = (i < n) ? deg[i] : 0;
    if (i < n) dinv[i] = rsqrtf((float)(v + 1));
    s[t] = v; __syncthreads();
    #pragma unroll
    for (int off = 128; off > 0; off >>= 1) {
        if (t < off) s[t] += s[t + off];
        __syncthreads();
    }
    if (t == 0) bsum[blockIdx.x] = s[0];
}

__global__ __launch_bounds__(256) void scan_top_kernel(int* __restrict__ bsum, int nb) {
    __shared__ int s[256];
    int t = threadIdx.x;
    int v = (t < nb) ? bsum[t] : 0;
    s[t] = v; __syncthreads();
    for (int off = 1; off < 256; off <<= 1) {
        int u = (t >= off) ? s[t - off] : 0;
        __syncthreads();
        s[t] += u;
        __syncthreads();
    }
    if (t < nb) bsum[t] = s[t] - v;
}

__global__ __launch_bounds__(256) void scan_write_kernel(const int* __restrict__ deg, const int* __restrict__ bsum,
                                                         int* __restrict__ rowptr, int* __restrict__ cursor, int n) {
    __shared__ int s[256];
    int t = threadIdx.x;
    int i = blockIdx.x * 256 + t;
    int v = (i < n) ? deg[i] : 0;
    s[t] = v; __syncthreads();
    for (int off = 1; off < 256; off <<= 1) {
        int u = (t >= off) ? s[t - off] : 0;
        __syncthreads();
        s[t] += u;
        __syncthreads();
    }
    int base = bsum[blockIdx.x];
    if (i < n) { int rp = base + s[t] - v; rowptr[i] = rp; cursor[i] = rp; }
    if (i == n - 1) rowptr[n] = base + s[t];
}

// ---------------- MFMA GEMM v4: 2-deep reg prefetch across RAW barriers ----------
// BM=128, BN=128, BK=64, 4 waves (2x2, 64x64 each), dbuf LDS 64 KiB.
// One raw s_barrier per step; barriers wait lgkmcnt only, so the 12 global
// loads issued at step t stay in flight across the barrier and are consumed
// (counted compiler vmcnt) at the END of step t+1 -- a full step of cover.
// LDS/frag indexing identical to R5 (verified, 0 bank conflicts).
#define GBM 128
#define GBK 64

typedef short ldsbuf_t[8][128][8];   // [k8][slot=row^k8][j]

template<int K, int COLOFF>
__device__ __forceinline__ void gemm_tile(const float* __restrict__ X, const short* __restrict__ Wt,
                                          short* __restrict__ xw,
                                          ldsbuf_t* As, ldsbuf_t* Bs,
                                          int tileIdx, int n) {
    constexpr int NT = K / GBK;       // 8 (mod1) or 4 (mod2), always even
    const int t    = threadIdx.x;
    const int lane = t & 63;
    const int wave = t >> 6;
    const int wr   = wave >> 1, wc = wave & 1;
    const int l15  = lane & 15, kof = lane >> 4;
    const int rowBase = tileIdx * GBM;

    // A staging: thread covers rows a_r+16i (i<8), float4 at k-offset a_kq
    const int a_r  = t >> 4;
    const int a_kq = (t & 15) * 4;
    const int a_k8 = a_kq >> 3;
    const int a_j  = a_kq & 7;
    // B staging: cols b_c0+32i (i<4), 16B frag at k8 chunk b_k8
    const int b_k8 = t & 7;
    const int b_c0 = t >> 3;

    const bool full = (rowBase + GBM <= n);
    const float* abase = X + (size_t)(rowBase + a_r) * K + a_kq;   // fast path
    const short* bptr  = Wt + (size_t)b_c0 * K + b_k8 * 8;

    float4 A0[8]; frag_ab B0[4];
    float4 A1[8]; frag_ab B1[4];

    auto issue = [&](float4 (&av)[8], frag_ab (&bv)[4], int kt) {
        if (full) {
            #pragma unroll
            for (int i = 0; i < 8; ++i)
                av[i] = *reinterpret_cast<const float4*>(abase + kt + (size_t)i * 16 * K);
        } else {
            #pragma unroll
            for (int i = 0; i < 8; ++i) {
                int g = rowBase + a_r + i * 16; if (g >= n) g = n - 1;
                av[i] = *reinterpret_cast<const float4*>(X + (size_t)g * K + kt + a_kq);
            }
        }
        #pragma unroll
        for (int i = 0; i < 4; ++i)
            bv[i] = *reinterpret_cast<const frag_ab*>(bptr + (size_t)i * 32 * K + kt);
    };
    auto wstage = [&](int buf, float4 (&av)[8], frag_ab (&bv)[4]) {
        #pragma unroll
        for (int i = 0; i < 8; ++i) {
            int r = a_r + i * 16;
            short4v p;
            p[0] = f2bf(av[i].x); p[1] = f2bf(av[i].y);
            p[2] = f2bf(av[i].z); p[3] = f2bf(av[i].w);
            *reinterpret_cast<short4v*>(&As[buf][a_k8][r ^ a_k8][a_j]) = p;
        }
        #pragma unroll
        for (int i = 0; i < 4; ++i)
            *reinterpret_cast<frag_ab*>(&Bs[buf][b_k8][(b_c0 + i * 32) ^ b_k8][0]) = bv[i];
    };

    frag_cd acc[4][4];
    #pragma unroll
    for (int i = 0; i < 4; ++i)
        #pragma unroll
        for (int j = 0; j < 4; ++j)
            acc[i][j] = (frag_cd){0.f, 0.f, 0.f, 0.f};

    auto compute = [&](int buf) {
        frag_ab afr[2][4], bfr[2][4];
        #pragma unroll
        for (int ks = 0; ks < 2; ++ks) {
            const int k8a = ks * 4 + kof;
            #pragma unroll
            for (int mf = 0; mf < 4; ++mf)
                afr[ks][mf] = *reinterpret_cast<const frag_ab*>(&As[buf][k8a][(wr * 64 + mf * 16 + l15) ^ k8a][0]);
            #pragma unroll
            for (int nf = 0; nf < 4; ++nf)
                bfr[ks][nf] = *reinterpret_cast<const frag_ab*>(&Bs[buf][k8a][(wc * 64 + nf * 16 + l15) ^ k8a][0]);
        }
        __builtin_amdgcn_s_setprio(1);
        #pragma unroll
        for (int ks = 0; ks < 2; ++ks)
            #pragma unroll
            for (int mf = 0; mf < 4; ++mf)
                #pragma unroll
                for (int nf = 0; nf < 4; ++nf)
                    acc[mf][nf] = __builtin_amdgcn_mfma_f32_16x16x32_bf16(bfr[ks][nf], afr[ks][mf], acc[mf][nf], 0, 0, 0);
        __builtin_amdgcn_s_setprio(0);
    };

    // prologue: tiles 0,1 in flight; stage tile 0
    issue(A0, B0, 0);
    if (NT > 1) issue(A1, B1, GBK);
    wstage(0, A0, B0);
    sync_lds();

    #pragma unroll
    for (int it = 0; it < NT; it += 2) {
        // even step: compute buf0(tile it); prefetch it+2; stage it+1 -> buf1
        if (it + 2 < NT) issue(A0, B0, (it + 2) * GBK);
        compute(0);
        if (it + 1 < NT) wstage(1, A1, B1);
        sync_lds();
        // odd step: compute buf1(tile it+1); prefetch it+3; stage it+2 -> buf0
        if (it + 3 < NT) issue(A1, B1, (it + 3) * GBK);
        if (it + 1 < NT) compute(1);
        if (it + 2 < NT) wstage(0, A0, B0);
        sync_lds();
    }

    // epilogue (no dinv here; gather applies norm)
    #pragma unroll
    for (int mf = 0; mf < 4; ++mf) {
        int orow = rowBase + wr * 64 + mf * 16 + l15;
        if (orow < n) {
            short* dst = xw + (size_t)orow * FTOT + COLOFF + wc * 64 + kof * 4;
            #pragma unroll
            for (int nf = 0; nf < 4; ++nf) {
                short4v pk;
                pk[0] = f2bf(acc[mf][nf][0]); pk[1] = f2bf(acc[mf][nf][1]);
                pk[2] = f2bf(acc[mf][nf][2]); pk[3] = f2bf(acc[mf][nf][3]);
                *reinterpret_cast<short4v*>(dst + nf * 16) = pk;
            }
        }
    }
}

// D1: gemm modality-1 blocks || hist blocks (independent work fused in one dispatch)
__global__ __launch_bounds__(256, 2) void g1_kernel(const float* __restrict__ x1, const short* __restrict__ w1t,
                                                    short* __restrict__ xw, const int* __restrict__ ei,
                                                    int* __restrict__ deg, int n, int e, int t1b, int nbh) {
    __shared__ ldsbuf_t As[2];
    __shared__ ldsbuf_t Bs[2];
    int b = blockIdx.x;
    if (b < t1b) {
        gemm_tile<IN1, 0>(x1, w1t, xw, As, Bs, b, n);
    } else {
        for (int i = (b - t1b) * 256 + threadIdx.x; i < e; i += nbh * 256)
            atomicAdd(&deg[ei[e + i]], 1);
    }
}

// D3: gemm modality-2 blocks || fill blocks
__global__ __launch_bounds__(256, 2) void g2_kernel(const float* __restrict__ x2, const short* __restrict__ w2t,
                                                    short* __restrict__ xw, const int* __restrict__ ei,
                                                    int* __restrict__ cursor, int* __restrict__ adj,
                                                    int n, int e, int t2b, int nbf) {
    __shared__ ldsbuf_t As[2];
    __shared__ ldsbuf_t Bs[2];
    int b = blockIdx.x;
    if (b < t2b) {
        gemm_tile<IN2, 128>(x2, w2t, xw, As, Bs, b, n);
    } else {
        for (int i = (b - t2b) * 256 + threadIdx.x; i < e; i += nbf * 256) {
            int src = ei[i];
            int dst = ei[e + i];
            int pos = atomicAdd(&cursor[dst], 1);
            adj[pos] = src;
        }
    }
}

// ---------------- gather + epilogue ----------------
// one wave per node; per-edge dinv[src] is a wave-uniform broadcast load.
__global__ __launch_bounds__(256) void gather_kernel(const unsigned short* __restrict__ xw,
                                                     const int* __restrict__ rowptr,
                                                     const int* __restrict__ adj,
                                                     const float* __restrict__ dinv,
                                                     const float* __restrict__ b1,
                                                     const float* __restrict__ b2,
                                                     float* __restrict__ out, int n) {
    int wid  = (int)((blockIdx.x * (size_t)blockDim.x + threadIdx.x) >> 6);
    int lane = threadIdx.x & 63;
    if (wid >= n) return;

    const ushort4* base = reinterpret_cast<const ushort4*>(xw);
    float ax = 0.f, ay = 0.f, az = 0.f, aw = 0.f;

    const int s = rowptr[wid], e = rowptr[wid + 1];
    int i = s;
    for (; i + 3 < e; i += 4) {
        int s0 = adj[i], s1 = adj[i + 1], s2 = adj[i + 2], s3 = adj[i + 3];
        float w0 = dinv[s0], w1 = dinv[s1], w2 = dinv[s2], w3 = dinv[s3];
        ushort4 v0 = base[(size_t)s0 * 64 + lane];
        ushort4 v1 = base[(size_t)s1 * 64 + lane];
        ushort4 v2 = base[(size_t)s2 * 64 + lane];
        ushort4 v3 = base[(size_t)s3 * 64 + lane];
        ax = fmaf(bf2f(v0.x), w0, fmaf(bf2f(v1.x), w1, fmaf(bf2f(v2.x), w2, fmaf(bf2f(v3.x), w3, ax))));
        ay = fmaf(bf2f(v0.y), w0, fmaf(bf2f(v1.y), w1, fmaf(bf2f(v2.y), w2, fmaf(bf2f(v3.y), w3, ay))));
        az = fmaf(bf2f(v0.z), w0, fmaf(bf2f(v1.z), w1, fmaf(bf2f(v2.z), w2, fmaf(bf2f(v3.z), w3, az))));
        aw = fmaf(bf2f(v0.w), w0, fmaf(bf2f(v1.w), w1, fmaf(bf2f(v2.w), w2, fmaf(bf2f(v3.w), w3, aw))));
    }
    for (; i < e; ++i) {
        int s0 = adj[i];
        float w0 = dinv[s0];
        ushort4 v0 = base[(size_t)s0 * 64 + lane];
        ax = fmaf(bf2f(v0.x), w0, ax); ay = fmaf(bf2f(v0.y), w0, ay);
        az = fmaf(bf2f(v0.z), w0, az); aw = fmaf(bf2f(v0.w), w0, aw);
    }
    float di = dinv[wid];
    {   // self-loop
        ushort4 v = base[(size_t)wid * 64 + lane];
        ax = fmaf(bf2f(v.x), di, ax); ay = fmaf(bf2f(v.y), di, ay);
        az = fmaf(bf2f(v.z), di, az); aw = fmaf(bf2f(v.w), di, aw);
    }
    float4 bias = (lane < 32) ? reinterpret_cast<const float4*>(b1)[lane]
                              : reinterpret_cast<const float4*>(b2)[lane - 32];
    float4 v;
    v.x = fmaxf(fmaf(ax, di, bias.x), 0.f);
    v.y = fmaxf(fmaf(ay, di, bias.y), 0.f);
    v.z = fmaxf(fmaf(az, di, bias.z), 0.f);
    v.w = fmaxf(fmaf(aw, di, bias.w), 0.f);

    float4 h;
    h.x = v.x + __shfl_xor(v.x, 32);
    h.y = v.y + __shfl_xor(v.y, 32);
    h.z = v.z + __shfl_xor(v.z, 32);
    h.w = v.w + __shfl_xor(v.w, 32);

    float m = fmaxf(fmaxf(h.x, h.y), fmaxf(h.z, h.w));
    #pragma unroll
    for (int off = 1; off <= 16; off <<= 1) m = fmaxf(m, __shfl_xor(m, off));
    float ssum = __expf(h.x - m) + __expf(h.y - m) + __expf(h.z - m) + __expf(h.w - m);
    #pragma unroll
    for (int off = 1; off <= 16; off <<= 1) ssum += __shfl_xor(ssum, off);
    float lse = m + __logf(ssum);

    if (lane < 32) {
        float4 y;
        y.x = h.x - lse; y.y = h.y - lse; y.z = h.z - lse; y.w = h.w - lse;
        reinterpret_cast<float4*>(out)[(size_t)wid * 32 + lane] = y;
    }
}

// ---------------- launcher ----------------
extern "C" void kernel_launch(void* const* d_in, const int* in_sizes, int n_in,
                              void* d_out, int out_size, void* d_ws, size_t ws_size,
                              hipStream_t stream) {
    const float* x1 = (const float*)d_in[0];
    const float* x2 = (const float*)d_in[1];
    const int*   ei = (const int*)d_in[2];
    const float* W1 = (const float*)d_in[3];
    const float* b1 = (const float*)d_in[4];
    const float* W2 = (const float*)d_in[5];
    const float* b2 = (const float*)d_in[6];
    float* out = (float*)d_out;

    const int n = in_sizes[0] / IN1;       // 50000
    const int e = in_sizes[2] / 2;         // 800000

    char* ws = (char*)d_ws;
    short* xw     = (short*)(ws + OFF_XW);
    short* w1t    = (short*)(ws + OFF_W1T);
    short* w2t    = (short*)(ws + OFF_W2T);
    int*   deg    = (int*)  (ws + OFF_DEG);
    float* dinv   = (float*)(ws + OFF_DINV);
    int*   rowptr = (int*)  (ws + OFF_ROWPTR);
    int*   cursor = (int*)  (ws + OFF_CURSOR);
    int*   bsum   = (int*)  (ws + OFF_BSUM);
    int*   adj    = (int*)  (ws + OFF_ADJ);

    const int nb_n = (n + 255) / 256;      // 196
    const int t1b  = (n + GBM - 1) / GBM;  // 391
    const int t2b  = t1b;
    const int nbh  = 391;                  // hist blocks (grid-stride)
    const int nbf  = 391;                  // fill blocks (grid-stride)

    // D0: W convert + deg zero
    wcvt_kernel<<<((IN1 + IN2) * NOUT + 255) / 256, 256, 0, stream>>>(W1, W2, w1t, w2t, deg, n);
    // D1: gemm(mod1) || hist
    g1_kernel<<<t1b + nbh, 256, 0, stream>>>(x1, w1t, xw, ei, deg, n, e, t1b, nbh);
    // D2: scan chain (deg -> dinv, rowptr, cursor)
    scan_part_kernel<<<nb_n, 256, 0, stream>>>(deg, dinv, bsum, n);
    scan_top_kernel<<<1, 256, 0, stream>>>(bsum, nb_n);
    scan_write_kernel<<<nb_n, 256, 0, stream>>>(deg, bsum, rowptr, cursor, n);
    // D3: gemm(mod2) || fill
    g2_kernel<<<t2b + nbf, 256, 0, stream>>>(x2, w2t, xw, ei, cursor, adj, n, e, t2b, nbf);
    // D4: gather + relu + add + log_softmax
    const int waves_per_block = 4;
    int gb = (n + waves_per_block - 1) / waves_per_block;
    gather_kernel<<<gb, 256, 0, stream>>>((const unsigned short*)xw, rowptr, adj, dinv, b1, b2, out, n);
}

// Round 9
// 188.616 us; speedup vs baseline: 1.1715x; 1.0822x over previous
//
#include <hip/hip_runtime.h>
#include <hip/hip_bf16.h>
#include <math.h>

#define NNODES 50000
#define NEDGES 800000
#define IN1 512
#define IN2 256
#define NOUT 128
#define FTOT 256   // combined feature width (two GCN branches)

typedef __attribute__((ext_vector_type(4))) short short4v;
typedef __attribute__((ext_vector_type(8))) short frag_ab;
typedef __attribute__((ext_vector_type(4))) float frag_cd;

// ---------------- workspace layout (bytes) ----------------
#define OFF_XW      ((size_t)0)           // N*256 bf16 = 25,600,000
#define OFF_W1T     ((size_t)25600000)    // 128x512 bf16 [col][k]
#define OFF_W2T     ((size_t)25731072)    // 128x256 bf16 [col][k]
#define OFF_DEG     ((size_t)25796608)    // N int
#define OFF_DINV    ((size_t)25996672)    // N f32
#define OFF_ROWPTR  ((size_t)26196736)    // (N+1) int
#define OFF_CURSOR  ((size_t)26396800)    // N int
#define OFF_BSUM    ((size_t)26596864)    // 256 int
#define OFF_ADJ     ((size_t)26600960)    // E int

__device__ __forceinline__ short f2bf(float f) {
    union { float f; unsigned u; } x; x.f = f;
    unsigned r = x.u + 0x7fffu + ((x.u >> 16) & 1u);   // RNE
    return (short)(r >> 16);
}
__device__ __forceinline__ float bf2f(unsigned short u) {
    union { unsigned u; float f; } x; x.u = ((unsigned)u) << 16;
    return x.f;
}

// ---------------- small kernels ----------------

__global__ __launch_bounds__(256) void wcvt_kernel(const float* __restrict__ W1, const float* __restrict__ W2,
                                                   short* __restrict__ w1t, short* __restrict__ w2t,
                                                   int* __restrict__ deg, int n) {
    int t = blockIdx.x * 256 + threadIdx.x;
    if (t < n) deg[t] = 0;
    if (t < IN1 * NOUT) {
        int c = t & 127, k = t >> 7;
        w1t[c * IN1 + k] = f2bf(W1[t]);
    } else if (t < (IN1 + IN2) * NOUT) {
        int u = t - IN1 * NOUT;
        int c = u & 127, k = u >> 7;
        w2t[c * IN2 + k] = f2bf(W2[u]);
    }
}

__global__ __launch_bounds__(256) void scan_part_kernel(const int* __restrict__ deg, float* __restrict__ dinv,
                                                        int* __restrict__ bsum, int n) {
    __shared__ int s[256];
    int t = threadIdx.x;
    int i = blockIdx.x * 256 + t;
    int v = (i < n) ? deg[i] : 0;
    if (i < n) dinv[i] = rsqrtf((float)(v + 1));
    s[t] = v; __syncthreads();
    #pragma unroll
    for (int off = 128; off > 0; off >>= 1) {
        if (t < off) s[t] += s[t + off];
        __syncthreads();
    }
    if (t == 0) bsum[blockIdx.x] = s[0];
}

__global__ __launch_bounds__(256) void scan_top_kernel(int* __restrict__ bsum, int nb) {
    __shared__ int s[256];
    int t = threadIdx.x;
    int v = (t < nb) ? bsum[t] : 0;
    s[t] = v; __syncthreads();
    for (int off = 1; off < 256; off <<= 1) {
        int u = (t >= off) ? s[t - off] : 0;
        __syncthreads();
        s[t] += u;
        __syncthreads();
    }
    if (t < nb) bsum[t] = s[t] - v;
}

__global__ __launch_bounds__(256) void scan_write_kernel(const int* __restrict__ deg, const int* __restrict__ bsum,
                                                         int* __restrict__ rowptr, int* __restrict__ cursor, int n) {
    __shared__ int s[256];
    int t = threadIdx.x;
    int i = blockIdx.x * 256 + t;
    int v = (i < n) ? deg[i] : 0;
    s[t] = v; __syncthreads();
    for (int off = 1; off < 256; off <<= 1) {
        int u = (t >= off) ? s[t - off] : 0;
        __syncthreads();
        s[t] += u;
        __syncthreads();
    }
    int base = bsum[blockIdx.x];
    if (i < n) { int rp = base + s[t] - v; rowptr[i] = rp; cursor[i] = rp; }
    if (i == n - 1) rowptr[n] = base + s[t];
}

// ---------------- MFMA GEMM v5: LDS-free, barrier-free streaming ----------------
// One wave owns 32 rows x 128 cols. B-frags (16B/lane) come straight from
// global/L2 (W is 192 KB, L2-hot). A streams 2x32B per row per K-step with a
// 1-step ping/pong prefetch in NAMED register sets (no runtime indexing).
// No __syncthreads anywhere -> waves fully independent, loads stay in flight.
template<int K, int COLOFF>
__device__ __forceinline__ void gemm_rows32(const float* __restrict__ X, const short* __restrict__ Wt,
                                            short* __restrict__ xw, int tile, int n) {
    constexpr int NSTEP = K / 32;    // 16 (mod1), 8 (mod2) -- always even
    const int lane = threadIdx.x & 63;
    const int l15 = lane & 15, kof = lane >> 4;
    const int r0 = tile * 32;
    int row0 = r0 + l15;      if (row0 >= n) row0 = n - 1;
    int row1 = r0 + 16 + l15; if (row1 >= n) row1 = n - 1;
    const float* a0p = X + (size_t)row0 * K + kof * 8;
    const float* a1p = X + (size_t)row1 * K + kof * 8;
    const short* bp  = Wt + (size_t)l15 * K + kof * 8;

    frag_cd acc0[8], acc1[8];
    #pragma unroll
    for (int cf = 0; cf < 8; ++cf) {
        acc0[cf] = (frag_cd){0.f, 0.f, 0.f, 0.f};
        acc1[cf] = (frag_cd){0.f, 0.f, 0.f, 0.f};
    }

    auto loadA = [&](int s, float4* m0, float4* m1) {
        m0[0] = *reinterpret_cast<const float4*>(a0p + s * 32);
        m0[1] = *reinterpret_cast<const float4*>(a0p + s * 32 + 4);
        m1[0] = *reinterpret_cast<const float4*>(a1p + s * 32);
        m1[1] = *reinterpret_cast<const float4*>(a1p + s * 32 + 4);
    };
    auto loadB = [&](int s, frag_ab* b) {
        #pragma unroll
        for (int cf = 0; cf < 8; ++cf)
            b[cf] = *reinterpret_cast<const frag_ab*>(bp + (size_t)cf * 16 * K + s * 32);
    };
    auto cvt = [&](const float4* m) -> frag_ab {
        frag_ab o;
        o[0] = f2bf(m[0].x); o[1] = f2bf(m[0].y); o[2] = f2bf(m[0].z); o[3] = f2bf(m[0].w);
        o[4] = f2bf(m[1].x); o[5] = f2bf(m[1].y); o[6] = f2bf(m[1].z); o[7] = f2bf(m[1].w);
        return o;
    };
    auto mmac = [&](const frag_ab* b, frag_ab fa0, frag_ab fa1) {
        __builtin_amdgcn_s_setprio(1);
        #pragma unroll
        for (int cf = 0; cf < 8; ++cf) {
            acc0[cf] = __builtin_amdgcn_mfma_f32_16x16x32_bf16(b[cf], fa0, acc0[cf], 0, 0, 0);
            acc1[cf] = __builtin_amdgcn_mfma_f32_16x16x32_bf16(b[cf], fa1, acc1[cf], 0, 0, 0);
        }
        __builtin_amdgcn_s_setprio(0);
    };

    // ping/pong named sets (compile-time indexed under full unroll)
    float4 pa0[2], pa1[2], qa0[2], qa1[2];
    frag_ab pb[8], qb[8];

    loadA(0, pa0, pa1);
    loadB(0, pb);
    #pragma unroll
    for (int s = 0; s < NSTEP; s += 2) {
        if (s + 1 < NSTEP) { loadA(s + 1, qa0, qa1); loadB(s + 1, qb); }
        mmac(pb, cvt(pa0), cvt(pa1));
        if (s + 2 < NSTEP) { loadA(s + 2, pa0, pa1); loadB(s + 2, pb); }
        if (s + 1 < NSTEP) mmac(qb, cvt(qa0), cvt(qa1));
    }

    // epilogue: lane holds rows {row0,row1}, cols kof*4 + cf*16 (+0..3)
    if (r0 + l15 < n) {
        short* dst = xw + (size_t)row0 * FTOT + COLOFF + kof * 4;
        #pragma unroll
        for (int cf = 0; cf < 8; ++cf) {
            short4v pk;
            pk[0] = f2bf(acc0[cf][0]); pk[1] = f2bf(acc0[cf][1]);
            pk[2] = f2bf(acc0[cf][2]); pk[3] = f2bf(acc0[cf][3]);
            *reinterpret_cast<short4v*>(dst + cf * 16) = pk;
        }
    }
    if (r0 + 16 + l15 < n) {
        short* dst = xw + (size_t)row1 * FTOT + COLOFF + kof * 4;
        #pragma unroll
        for (int cf = 0; cf < 8; ++cf) {
            short4v pk;
            pk[0] = f2bf(acc1[cf][0]); pk[1] = f2bf(acc1[cf][1]);
            pk[2] = f2bf(acc1[cf][2]); pk[3] = f2bf(acc1[cf][3]);
            *reinterpret_cast<short4v*>(dst + cf * 16) = pk;
        }
    }
}

// D1: gemm(mod1) waves || hist waves. No barriers in either path -> mixed
// wave roles inside a block are safe. NOTE the strict role guard: the grid's
// padding tail wave must do NOTHING (R8 bug: it aliased hist wave 0's stride
// pattern and double-counted edges).
__global__ __launch_bounds__(256, 2) void g1_kernel(const float* __restrict__ x1, const short* __restrict__ w1t,
                                                    short* __restrict__ xw, const int* __restrict__ ei,
                                                    int* __restrict__ deg, int n, int e, int t1w, int nhw) {
    int w = blockIdx.x * 4 + (threadIdx.x >> 6);
    if (w < t1w) {
        gemm_rows32<IN1, 0>(x1, w1t, xw, w, n);
    } else if (w < t1w + nhw) {
        int lane = threadIdx.x & 63;
        for (int i = (w - t1w) * 64 + lane; i < e; i += nhw * 64)
            atomicAdd(&deg[ei[e + i]], 1);
    }
}

// D3: gemm(mod2) waves || fill waves (same strict guard)
__global__ __launch_bounds__(256, 2) void g2_kernel(const float* __restrict__ x2, const short* __restrict__ w2t,
                                                    short* __restrict__ xw, const int* __restrict__ ei,
                                                    int* __restrict__ cursor, int* __restrict__ adj,
                                                    int n, int e, int t2w, int nfw) {
    int w = blockIdx.x * 4 + (threadIdx.x >> 6);
    if (w < t2w) {
        gemm_rows32<IN2, 128>(x2, w2t, xw, w, n);
    } else if (w < t2w + nfw) {
        int lane = threadIdx.x & 63;
        for (int i = (w - t2w) * 64 + lane; i < e; i += nfw * 64) {
            int src = ei[i];
            int dst = ei[e + i];
            int pos = atomicAdd(&cursor[dst], 1);
            adj[pos] = src;
        }
    }
}

// ---------------- gather + epilogue ----------------
__global__ __launch_bounds__(256) void gather_kernel(const unsigned short* __restrict__ xw,
                                                     const int* __restrict__ rowptr,
                                                     const int* __restrict__ adj,
                                                     const float* __restrict__ dinv,
                                                     const float* __restrict__ b1,
                                                     const float* __restrict__ b2,
                                                     float* __restrict__ out, int n) {
    int wid  = (int)((blockIdx.x * (size_t)blockDim.x + threadIdx.x) >> 6);
    int lane = threadIdx.x & 63;
    if (wid >= n) return;

    const ushort4* base = reinterpret_cast<const ushort4*>(xw);
    float ax = 0.f, ay = 0.f, az = 0.f, aw = 0.f;

    const int s = rowptr[wid], e = rowptr[wid + 1];
    int i = s;
    for (; i + 3 < e; i += 4) {
        int s0 = adj[i], s1 = adj[i + 1], s2 = adj[i + 2], s3 = adj[i + 3];
        float w0 = dinv[s0], w1 = dinv[s1], w2 = dinv[s2], w3 = dinv[s3];
        ushort4 v0 = base[(size_t)s0 * 64 + lane];
        ushort4 v1 = base[(size_t)s1 * 64 + lane];
        ushort4 v2 = base[(size_t)s2 * 64 + lane];
        ushort4 v3 = base[(size_t)s3 * 64 + lane];
        ax = fmaf(bf2f(v0.x), w0, fmaf(bf2f(v1.x), w1, fmaf(bf2f(v2.x), w2, fmaf(bf2f(v3.x), w3, ax))));
        ay = fmaf(bf2f(v0.y), w0, fmaf(bf2f(v1.y), w1, fmaf(bf2f(v2.y), w2, fmaf(bf2f(v3.y), w3, ay))));
        az = fmaf(bf2f(v0.z), w0, fmaf(bf2f(v1.z), w1, fmaf(bf2f(v2.z), w2, fmaf(bf2f(v3.z), w3, az))));
        aw = fmaf(bf2f(v0.w), w0, fmaf(bf2f(v1.w), w1, fmaf(bf2f(v2.w), w2, fmaf(bf2f(v3.w), w3, aw))));
    }
    for (; i < e; ++i) {
        int s0 = adj[i];
        float w0 = dinv[s0];
        ushort4 v0 = base[(size_t)s0 * 64 + lane];
        ax = fmaf(bf2f(v0.x), w0, ax); ay = fmaf(bf2f(v0.y), w0, ay);
        az = fmaf(bf2f(v0.z), w0, az); aw = fmaf(bf2f(v0.w), w0, aw);
    }
    float di = dinv[wid];
    {   // self-loop
        ushort4 v = base[(size_t)wid * 64 + lane];
        ax = fmaf(bf2f(v.x), di, ax); ay = fmaf(bf2f(v.y), di, ay);
        az = fmaf(bf2f(v.z), di, az); aw = fmaf(bf2f(v.w), di, aw);
    }
    float4 bias = (lane < 32) ? reinterpret_cast<const float4*>(b1)[lane]
                              : reinterpret_cast<const float4*>(b2)[lane - 32];
    float4 v;
    v.x = fmaxf(fmaf(ax, di, bias.x), 0.f);
    v.y = fmaxf(fmaf(ay, di, bias.y), 0.f);
    v.z = fmaxf(fmaf(az, di, bias.z), 0.f);
    v.w = fmaxf(fmaf(aw, di, bias.w), 0.f);

    float4 h;
    h.x = v.x + __shfl_xor(v.x, 32);
    h.y = v.y + __shfl_xor(v.y, 32);
    h.z = v.z + __shfl_xor(v.z, 32);
    h.w = v.w + __shfl_xor(v.w, 32);

    float m = fmaxf(fmaxf(h.x, h.y), fmaxf(h.z, h.w));
    #pragma unroll
    for (int off = 1; off <= 16; off <<= 1) m = fmaxf(m, __shfl_xor(m, off));
    float ssum = __expf(h.x - m) + __expf(h.y - m) + __expf(h.z - m) + __expf(h.w - m);
    #pragma unroll
    for (int off = 1; off <= 16; off <<= 1) ssum += __shfl_xor(ssum, off);
    float lse = m + __logf(ssum);

    if (lane < 32) {
        float4 y;
        y.x = h.x - lse; y.y = h.y - lse; y.z = h.z - lse; y.w = h.w - lse;
        reinterpret_cast<float4*>(out)[(size_t)wid * 32 + lane] = y;
    }
}

// ---------------- launcher ----------------
extern "C" void kernel_launch(void* const* d_in, const int* in_sizes, int n_in,
                              void* d_out, int out_size, void* d_ws, size_t ws_size,
                              hipStream_t stream) {
    const float* x1 = (const float*)d_in[0];
    const float* x2 = (const float*)d_in[1];
    const int*   ei = (const int*)d_in[2];
    const float* W1 = (const float*)d_in[3];
    const float* b1 = (const float*)d_in[4];
    const float* W2 = (const float*)d_in[5];
    const float* b2 = (const float*)d_in[6];
    float* out = (float*)d_out;

    const int n = in_sizes[0] / IN1;       // 50000
    const int e = in_sizes[2] / 2;         // 800000

    char* ws = (char*)d_ws;
    short* xw     = (short*)(ws + OFF_XW);
    short* w1t    = (short*)(ws + OFF_W1T);
    short* w2t    = (short*)(ws + OFF_W2T);
    int*   deg    = (int*)  (ws + OFF_DEG);
    float* dinv   = (float*)(ws + OFF_DINV);
    int*   rowptr = (int*)  (ws + OFF_ROWPTR);
    int*   cursor = (int*)  (ws + OFF_CURSOR);
    int*   bsum   = (int*)  (ws + OFF_BSUM);
    int*   adj    = (int*)  (ws + OFF_ADJ);

    const int nb_n = (n + 255) / 256;      // 196
    const int t1w  = (n + 31) / 32;        // 1563 gemm waves (mod1)
    const int t2w  = t1w;                  // 1563 gemm waves (mod2)
    const int nhw  = 512;                  // hist waves
    const int nfw  = 512;                  // fill waves

    // D0: W convert + deg zero
    wcvt_kernel<<<((IN1 + IN2) * NOUT + 255) / 256, 256, 0, stream>>>(W1, W2, w1t, w2t, deg, n);
    // D1: gemm(mod1) || hist
    g1_kernel<<<(t1w + nhw + 3) / 4, 256, 0, stream>>>(x1, w1t, xw, ei, deg, n, e, t1w, nhw);
    // D2: scan chain (deg -> dinv, rowptr, cursor)
    scan_part_kernel<<<nb_n, 256, 0, stream>>>(deg, dinv, bsum, n);
    scan_top_kernel<<<1, 256, 0, stream>>>(bsum, nb_n);
    scan_write_kernel<<<nb_n, 256, 0, stream>>>(deg, bsum, rowptr, cursor, n);
    // D3: gemm(mod2) || fill
    g2_kernel<<<(t2w + nfw + 3) / 4, 256, 0, stream>>>(x2, w2t, xw, ei, cursor, adj, n, e, t2w, nfw);
    // D4: gather + relu + add + log_softmax
    const int waves_per_block = 4;
    int gb = (n + waves_per_block - 1) / waves_per_block;
    gather_kernel<<<gb, 256, 0, stream>>>((const unsigned short*)xw, rowptr, adj, dinv, b1, b2, out, n);
}